// Round 2
// baseline (193.299 us; speedup 1.0000x reference)
//
#include <hip/hip_runtime.h>

typedef short short8 __attribute__((ext_vector_type(8)));
typedef float f32x4 __attribute__((ext_vector_type(4)));

#define N_NODES   100000
#define E_KEEP    1000000
#define E_TOTAL_N 1100000
#define EDGE_OUT_BASE 12800000L

__device__ __forceinline__ unsigned short f2bf(float f) {
  unsigned int u = __builtin_bit_cast(unsigned int, f);
  u += 0x7fffu + ((u >> 16) & 1u);   // round-to-nearest-even
  return (unsigned short)(u >> 16);
}

// nw2/ew2 are fp32 [128][128]. Write bf16 W2^T into ws: node at [0:16384],
// edge at [16384:32768], row-major W2T[n][k] so MFMA A-fragments are
// contiguous 16B loads.
__global__ void transpose_w2(const float* __restrict__ nw2,
                             const float* __restrict__ ew2,
                             unsigned short* __restrict__ ws) {
  int idx = blockIdx.x * 256 + threadIdx.x;
  for (int i = idx; i < 32768; i += 8192) {
    int m = i >> 14;          // 0 = node, 1 = edge
    int w = i & 16383;
    int k = w >> 7;
    int n = w & 127;
    const float* src = m ? ew2 : nw2;
    ws[m * 16384 + n * 128 + k] = f2bf(src[w]);  // W2T[n][k] = W2[k][n]
  }
}

// ---------------- edge path: attr = [dx, dy, norm], K1 = 3 ----------------
__device__ __forceinline__ void run_edges(
    const float* __restrict__ pos,
    const int* __restrict__ ei,
    const float* __restrict__ w1,
    const float* __restrict__ b1,
    const float* __restrict__ b2,
    const unsigned short* __restrict__ w2t,
    float* __restrict__ outp,
    int bid)
{
  __shared__ float w1f[3 * 128];
  __shared__ float b1f[128];
  __shared__ float b2f[128];
  int t = threadIdx.x;
  if (t < 128) { b1f[t] = b1[t]; b2f[t] = b2[t]; }
  for (int i = t; i < 384; i += 256) w1f[i] = w1[i];
  __syncthreads();

  const int lane = t & 63;
  const int wid  = t >> 6;
  const int rg   = wid & 1;   // row group (16 rows each)
  const int wc   = wid >> 1;  // col group (64 cols each)
  const int c    = lane & 15;
  const int g    = lane >> 4;

  // W2^T fragments as MFMA A operand: A[m][k], lane holds m = base+c, k = kk*32 + g*8 ..+8
  short8 wfrag[4][4];
#pragma unroll
  for (int nf = 0; nf < 4; ++nf)
#pragma unroll
    for (int kk = 0; kk < 4; ++kk)
      wfrag[nf][kk] = *(const short8*)(w2t + (wc * 64 + nf * 16 + c) * 128 + kk * 32 + g * 8);

  // hoist all gathers for the whole block
  int srcs[8], dsts[8];
#pragma unroll
  for (int s = 0; s < 8; ++s) {
    int r  = bid * 256 + s * 32 + rg * 16 + c;
    int rl = r < E_KEEP ? r : E_KEEP - 1;
    srcs[s] = ei[rl];
    dsts[s] = ei[E_TOTAL_N + rl];
  }
  float pxa[8], pya[8], pxb[8], pyb[8];
#pragma unroll
  for (int s = 0; s < 8; ++s) {
    pxa[s] = pos[srcs[s] * 3];
    pya[s] = pos[srcs[s] * 3 + 1];
    pxb[s] = pos[dsts[s] * 3];
    pyb[s] = pos[dsts[s] * 3 + 1];
  }

#pragma unroll
  for (int s = 0; s < 8; ++s) {
    int row0 = bid * 256 + s * 32 + rg * 16;
    if (row0 >= E_KEEP) continue;

    float ax = pxa[s] - pxb[s];
    float ay = pya[s] - pyb[s];
    float an = sqrtf(ax * ax + ay * ay);

    // h1 in B-fragment layout: lane owns row (l&15), k = kk*32 + g*8 + j
    short8 hfrag[4];
#pragma unroll
    for (int kk = 0; kk < 4; ++kk) {
      int k0 = kk * 32 + g * 8;
      const f32x4* bp  = (const f32x4*)&b1f[k0];
      f32x4 h0 = bp[0], h1 = bp[1];
      const f32x4* w0p = (const f32x4*)&w1f[k0];
      const f32x4* w1p = (const f32x4*)&w1f[128 + k0];
      const f32x4* w2p = (const f32x4*)&w1f[256 + k0];
      h0 += ax * w0p[0]; h1 += ax * w0p[1];
      h0 += ay * w1p[0]; h1 += ay * w1p[1];
      h0 += an * w2p[0]; h1 += an * w2p[1];
      short8 hf;
#pragma unroll
      for (int j = 0; j < 4; ++j) hf[j]     = (short)f2bf(fmaxf(h0[j], 0.f));
#pragma unroll
      for (int j = 0; j < 4; ++j) hf[4 + j] = (short)f2bf(fmaxf(h1[j], 0.f));
      hfrag[kk] = hf;
    }

    f32x4 acc[4] = {};
#pragma unroll
    for (int kk = 0; kk < 4; ++kk)
#pragma unroll
      for (int nf = 0; nf < 4; ++nf)
        acc[nf] = __builtin_amdgcn_mfma_f32_16x16x32_bf16(wfrag[nf][kk], hfrag[kk], acc[nf], 0, 0, 0);

    int r = row0 + c;
    if (r < E_KEEP) {
      long base = EDGE_OUT_BASE + (long)r * 128;
#pragma unroll
      for (int nf = 0; nf < 4; ++nf) {
        int col0 = wc * 64 + nf * 16 + g * 4;  // D: lane holds 4 consecutive cols of its row
        f32x4 bv = *(const f32x4*)&b2f[col0];
        f32x4 o = acc[nf] + bv;
        *(f32x4*)(outp + base + col0) = o;
      }
    }
  }
}

// ---------------- node path: attr = x row, K1 = 7 ----------------
__device__ __forceinline__ void run_nodes(
    const float* __restrict__ xin,
    const float* __restrict__ w1,
    const float* __restrict__ b1,
    const float* __restrict__ b2,
    const unsigned short* __restrict__ w2t,
    float* __restrict__ outp,
    int bid)
{
  __shared__ float w1fn[7 * 128];
  __shared__ float b1fn[128];
  __shared__ float b2fn[128];
  int t = threadIdx.x;
  if (t < 128) { b1fn[t] = b1[t]; b2fn[t] = b2[t]; }
  for (int i = t; i < 896; i += 256) w1fn[i] = w1[i];
  __syncthreads();

  const int lane = t & 63;
  const int wid  = t >> 6;
  const int rg   = wid & 1;
  const int wc   = wid >> 1;
  const int c    = lane & 15;
  const int g    = lane >> 4;

  short8 wfrag[4][4];
#pragma unroll
  for (int nf = 0; nf < 4; ++nf)
#pragma unroll
    for (int kk = 0; kk < 4; ++kk)
      wfrag[nf][kk] = *(const short8*)(w2t + (wc * 64 + nf * 16 + c) * 128 + kk * 32 + g * 8);

#pragma unroll
  for (int s = 0; s < 8; ++s) {
    int row0 = bid * 256 + s * 32 + rg * 16;
    if (row0 >= N_NODES) continue;
    int r  = row0 + c;
    int rl = r < N_NODES ? r : N_NODES - 1;

    float a[7];
#pragma unroll
    for (int cc = 0; cc < 7; ++cc) a[cc] = xin[rl * 7 + cc];

    short8 hfrag[4];
#pragma unroll
    for (int kk = 0; kk < 4; ++kk) {
      int k0 = kk * 32 + g * 8;
      const f32x4* bp = (const f32x4*)&b1fn[k0];
      f32x4 h0 = bp[0], h1 = bp[1];
#pragma unroll
      for (int cc = 0; cc < 7; ++cc) {
        const f32x4* wp = (const f32x4*)&w1fn[cc * 128 + k0];
        h0 += a[cc] * wp[0];
        h1 += a[cc] * wp[1];
      }
      short8 hf;
#pragma unroll
      for (int j = 0; j < 4; ++j) hf[j]     = (short)f2bf(fmaxf(h0[j], 0.f));
#pragma unroll
      for (int j = 0; j < 4; ++j) hf[4 + j] = (short)f2bf(fmaxf(h1[j], 0.f));
      hfrag[kk] = hf;
    }

    f32x4 acc[4] = {};
#pragma unroll
    for (int kk = 0; kk < 4; ++kk)
#pragma unroll
      for (int nf = 0; nf < 4; ++nf)
        acc[nf] = __builtin_amdgcn_mfma_f32_16x16x32_bf16(wfrag[nf][kk], hfrag[kk], acc[nf], 0, 0, 0);

    if (r < N_NODES) {
      long base = (long)r * 128;
#pragma unroll
      for (int nf = 0; nf < 4; ++nf) {
        int col0 = wc * 64 + nf * 16 + g * 4;
        f32x4 bv = *(const f32x4*)&b2fn[col0];
        f32x4 o = acc[nf] + bv;
        *(f32x4*)(outp + base + col0) = o;
      }
    }
  }
}

__global__ __launch_bounds__(256, 2) void encoder_kernel(
    const float* __restrict__ x,
    const float* __restrict__ pos,
    const int* __restrict__ ei,
    const float* __restrict__ nw1,
    const float* __restrict__ nb1,
    const float* __restrict__ nb2,
    const float* __restrict__ ew1,
    const float* __restrict__ eb1,
    const float* __restrict__ eb2,
    const unsigned short* __restrict__ ws,
    float* __restrict__ outp,
    int nodeBlocks)
{
  int bid = blockIdx.x;
  if (bid < nodeBlocks) {
    run_nodes(x, nw1, nb1, nb2, ws, outp, bid);
  } else {
    run_edges(pos, ei, ew1, eb1, eb2, ws + 16384, outp, bid - nodeBlocks);
  }
}

extern "C" void kernel_launch(void* const* d_in, const int* in_sizes, int n_in,
                              void* d_out, int out_size, void* d_ws, size_t ws_size,
                              hipStream_t stream) {
  const float* x   = (const float*)d_in[0];
  const float* pos = (const float*)d_in[1];
  const int*   ei  = (const int*)d_in[2];
  const float* nw1 = (const float*)d_in[3];
  const float* nb1 = (const float*)d_in[4];
  const float* nw2 = (const float*)d_in[5];
  const float* nb2 = (const float*)d_in[6];
  const float* ew1 = (const float*)d_in[7];
  const float* eb1 = (const float*)d_in[8];
  const float* ew2 = (const float*)d_in[9];
  const float* eb2 = (const float*)d_in[10];
  unsigned short* ws   = (unsigned short*)d_ws;
  float*          outp = (float*)d_out;

  transpose_w2<<<32, 256, 0, stream>>>(nw2, ew2, ws);

  int nodeBlocks = (N_NODES + 255) / 256;  // 391
  int edgeBlocks = (E_KEEP + 255) / 256;   // 3907
  encoder_kernel<<<nodeBlocks + edgeBlocks, 256, 0, stream>>>(
      x, pos, ei, nw1, nb1, nb2, ew1, eb1, eb2, ws, outp, nodeBlocks);
}